// Round 11
// baseline (638.918 us; speedup 1.0000x reference)
//
#include <hip/hip_runtime.h>

#define NP 30000
#define NA 30000
#define EDG 400000
#define HD 128          // H*D
#define LRELU_ALPHA 0.2f
#define NODE_STRIDE 30016   // padded per-type stride for count/cursor/offset arrays (ints)
#define TILE 32             // rows per fp32-GEMM block (4 rows/thread, 4 waves)
#define BPJ 938             // blocks per fp32-GEMM job = ceil(30000/32)
#define MTILE 64            // rows per MFMA block
#define MBPJ 469            // ceil(30000/64)
#define WS_OFF 16384        // byte offset of W region in MFMA LDS

typedef __attribute__((ext_vector_type(8))) short short8;
typedef __attribute__((ext_vector_type(4))) float f32x4;

__device__ __forceinline__ float lrelu(float x) { return x > 0.f ? x : LRELU_ALPHA * x; }

// float -> bf16 with round-to-nearest-even (inputs finite)
__device__ __forceinline__ unsigned short f2bf(float f) {
    unsigned u = __float_as_uint(f);
    u += 0x7fffu + ((u >> 16) & 1u);
    return (unsigned short)(u >> 16);
}

// ================= MFMA bf16 GEMM for the 4 edge-type tables =================
// (unchanged from round 8 — verified: passes with absmax 0.0156)
struct MJob {
    const float* A; const float* W; const float* bias;
    unsigned short* C; const float* a1; float* es;
};
struct MJobs { MJob j[4]; };

__launch_bounds__(256)
__global__ void gemm_mfma(MJobs js)
{
    const MJob J = js.j[blockIdx.y];
    __shared__ alignas(16) char lds[49152];
    const int t = threadIdx.x;
    const int row0 = blockIdx.x * MTILE;
    const int M = NP;

    // ---- stage A tile: fp32 -> bf16, swizzled ----
    #pragma unroll
    for (int i = 0; i < 4; ++i) {
        int c = t + i * 256;            // 1024 chunks of 8 elements
        int row = c >> 4, k0 = (c & 15) * 8;
        int gr = row0 + row;
        float4 v0 = make_float4(0.f,0.f,0.f,0.f), v1 = v0;
        if (gr < M) {
            v0 = reinterpret_cast<const float4*>(J.A)[(size_t)gr * 32 + (k0 >> 2)];
            v1 = reinterpret_cast<const float4*>(J.A)[(size_t)gr * 32 + (k0 >> 2) + 1];
        }
        short8 p;
        p[0]=f2bf(v0.x); p[1]=f2bf(v0.y); p[2]=f2bf(v0.z); p[3]=f2bf(v0.w);
        p[4]=f2bf(v1.x); p[5]=f2bf(v1.y); p[6]=f2bf(v1.z); p[7]=f2bf(v1.w);
        int byte = (row * 256 + k0 * 2) ^ ((row & 7) << 4);
        *reinterpret_cast<short8*>(lds + byte) = p;
    }
    // ---- stage W transposed: WsT[col][k] = W[k][col], fp32 -> bf16, swizzled ----
    {
        int c4 = (t & 31) * 4;          // 4 columns
        int kk = (t >> 5) * 16;         // 16 k's
        unsigned short wb[4][16];
        #pragma unroll
        for (int k = 0; k < 16; ++k) {
            float4 v = reinterpret_cast<const float4*>(J.W)[(kk + k) * 32 + (c4 >> 2)];
            wb[0][k]=f2bf(v.x); wb[1][k]=f2bf(v.y); wb[2][k]=f2bf(v.z); wb[3][k]=f2bf(v.w);
        }
        #pragma unroll
        for (int j = 0; j < 4; ++j) {
            int col = c4 + j;
            short8 s0, s1;
            #pragma unroll
            for (int q = 0; q < 8; ++q) { s0[q] = (short)wb[j][q]; s1[q] = (short)wb[j][q+8]; }
            int inner = col * 256 + kk * 2;
            int x = (col & 7) << 4;
            *reinterpret_cast<short8*>(lds + WS_OFF + ((inner)      ^ x)) = s0;
            *reinterpret_cast<short8*>(lds + WS_OFF + ((inner + 16) ^ x)) = s1;
        }
    }
    __syncthreads();

    const int l = t & 63, w = t >> 6;
    f32x4 acc[8];
    #pragma unroll
    for (int ct = 0; ct < 8; ++ct) {
        float bv = J.bias[ct * 16 + (l & 15)];
        acc[ct] = (f32x4){bv, bv, bv, bv};
    }
    const int arow = w * 16 + (l & 15);
    const int abase = arow * 256 + ((l >> 4) * 16);
    const int axor = (arow & 7) << 4;
    const int bxor = ((l & 15) & 7) << 4;
    #pragma unroll
    for (int kc = 0; kc < 4; ++kc) {
        short8 af = *reinterpret_cast<const short8*>(lds + ((abase + kc * 64) ^ axor));
        #pragma unroll
        for (int ct = 0; ct < 8; ++ct) {
            int binner = (ct * 16 + (l & 15)) * 256 + kc * 64 + ((l >> 4) * 16);
            short8 bf8 = *reinterpret_cast<const short8*>(lds + WS_OFF + (binner ^ bxor));
            acc[ct] = __builtin_amdgcn_mfma_f32_16x16x32_bf16(af, bf8, acc[ct], 0, 0, 0);
        }
    }
    // ---- C store (bf16) ----
    #pragma unroll
    for (int r = 0; r < 4; ++r) {
        int grow = row0 + w * 16 + (l >> 4) * 4 + r;
        if (grow < M) {
            #pragma unroll
            for (int ct = 0; ct < 8; ++ct)
                J.C[(size_t)grow * 128 + ct * 16 + (l & 15)] = f2bf(acc[ct][r]);
        }
    }
    // ---- es: per-head dots from fp32 acc ----
    #pragma unroll
    for (int h = 0; h < 4; ++h) {
        float alo = J.a1[h * 32 + (l & 15)];
        float ahi = J.a1[h * 32 + 16 + (l & 15)];
        #pragma unroll
        for (int r = 0; r < 4; ++r) {
            float p = acc[2*h][r] * alo + acc[2*h+1][r] * ahi;
            p += __shfl_xor(p, 1); p += __shfl_xor(p, 2);
            p += __shfl_xor(p, 4); p += __shfl_xor(p, 8);
            int grow = row0 + w * 16 + (l >> 4) * 4 + r;
            if ((l & 15) == 0 && grow < M) J.es[grow * 4 + h] = p;
        }
    }
}

// ================= fp32 GEMM (selves + state path), 4x4 thread tile =================
// Thread tile: 4 rows x 4 CONSECUTIVE cols -> W loads are float4 (coalesced 512B
// per 32-lane group, L2-resident) and A frags are b128: per 4-k chunk
// 4 global float4 + 4 LDS b128 for 64 FMAs (1 mem-op : 8 FMA; round-8 was 1:2).
// rowg = t>>5 (rows rowg*4..+3), c4 = (t&31)*4, head of a col group = (t&31)>>3.
// mode 0: write C + per-head rowdots a1->o1, a2->o2 (xor 1,2,4 butterfly in the
//         8-lane head group). mode 2: state aggregation epilogue.
struct GJob {
    const float* A; const float* W; const float* bias;
    float* C;
    const float* a1; float* o1;
    const float* a2; float* o2;
    int mode;
};
struct GJobs { GJob j[4]; };

__launch_bounds__(256)
__global__ void gemm_multi(GJobs js)
{
    const GJob J = js.j[blockIdx.y];
    __shared__ float As[TILE * 128];   // 16 KB
    __shared__ float sred[8][128];     // state-mode block reduce (per row-group)
    __shared__ float dred[8][4];
    const int t = threadIdx.x;
    const int row0 = blockIdx.x * TILE;
    const int M = NP;
    #pragma unroll
    for (int i = 0; i < 4; ++i) {
        int f4 = t + i * 256;
        int r = f4 >> 5, c4i = f4 & 31;
        int gr = row0 + r;
        float4 v = make_float4(0.f, 0.f, 0.f, 0.f);
        if (gr < M) v = reinterpret_cast<const float4*>(J.A)[(size_t)gr * 32 + c4i];
        reinterpret_cast<float4*>(As)[f4] = v;
    }
    __syncthreads();
    const int rowg = t >> 5;        // 0..7 ; rows rowg*4 .. rowg*4+3
    const int c4 = (t & 31) * 4;    // cols c4 .. c4+3
    float4 acc[4];
    #pragma unroll
    for (int r = 0; r < 4; ++r) acc[r] = make_float4(0.f, 0.f, 0.f, 0.f);
    const float* Asr = &As[rowg * 4 * 128];
    const float* W = J.W;
    for (int k = 0; k < 128; k += 4) {
        float4 w0 = *reinterpret_cast<const float4*>(&W[(k+0)*128 + c4]);
        float4 w1 = *reinterpret_cast<const float4*>(&W[(k+1)*128 + c4]);
        float4 w2 = *reinterpret_cast<const float4*>(&W[(k+2)*128 + c4]);
        float4 w3 = *reinterpret_cast<const float4*>(&W[(k+3)*128 + c4]);
        #pragma unroll
        for (int r = 0; r < 4; ++r) {
            float4 a = *reinterpret_cast<const float4*>(&Asr[r * 128 + k]);
            acc[r].x += a.x*w0.x + a.y*w1.x + a.z*w2.x + a.w*w3.x;
            acc[r].y += a.x*w0.y + a.y*w1.y + a.z*w2.y + a.w*w3.y;
            acc[r].z += a.x*w0.z + a.y*w1.z + a.z*w2.z + a.w*w3.z;
            acc[r].w += a.x*w0.w + a.y*w1.w + a.z*w2.w + a.w*w3.w;
        }
    }
    {
        float4 bv = *reinterpret_cast<const float4*>(&J.bias[c4]);
        #pragma unroll
        for (int r = 0; r < 4; ++r) {
            acc[r].x += bv.x; acc[r].y += bv.y; acc[r].z += bv.z; acc[r].w += bv.w;
        }
    }
    const int h = (t & 31) >> 3;   // head of this col group

    if (J.mode != 2) {
        // ---- C store (float4, coalesced) ----
        #pragma unroll
        for (int r = 0; r < 4; ++r) {
            int gr = row0 + rowg * 4 + r;
            if (gr < M) *reinterpret_cast<float4*>(&J.C[(size_t)gr * 128 + c4]) = acc[r];
        }
        // ---- per-head rowdots ----
        float4 a1v = *reinterpret_cast<const float4*>(&J.a1[c4]);
        float4 a2v = *reinterpret_cast<const float4*>(&J.a2[c4]);
        #pragma unroll
        for (int r = 0; r < 4; ++r) {
            int node = row0 + rowg * 4 + r;
            float p1 = acc[r].x*a1v.x + acc[r].y*a1v.y + acc[r].z*a1v.z + acc[r].w*a1v.w;
            float p2 = acc[r].x*a2v.x + acc[r].y*a2v.y + acc[r].z*a2v.z + acc[r].w*a2v.w;
            p1 += __shfl_xor(p1, 1); p1 += __shfl_xor(p1, 2); p1 += __shfl_xor(p1, 4);
            p2 += __shfl_xor(p2, 1); p2 += __shfl_xor(p2, 2); p2 += __shfl_xor(p2, 4);
            if ((t & 7) == 0 && node < M) {
                J.o1[node * 4 + h] = p1;
                J.o2[node * 4 + h] = p2;
            }
        }
    } else {
        // ---- state aggregation epilogue ----
        float4 asv = *reinterpret_cast<const float4*>(&J.a1[c4]);
        float eh = J.a2[h];
        float4 wsac = make_float4(0.f, 0.f, 0.f, 0.f);
        float dsum = 0.f;
        #pragma unroll
        for (int r = 0; r < 4; ++r) {
            int node = row0 + rowg * 4 + r;
            float p = acc[r].x*asv.x + acc[r].y*asv.y + acc[r].z*asv.z + acc[r].w*asv.w;
            p += __shfl_xor(p, 1); p += __shfl_xor(p, 2); p += __shfl_xor(p, 4);
            float wv = (node < M) ? __expf(lrelu(p + eh)) : 0.f;
            wsac.x += wv * acc[r].x; wsac.y += wv * acc[r].y;
            wsac.z += wv * acc[r].z; wsac.w += wv * acc[r].w;
            dsum += wv;
        }
        *reinterpret_cast<float4*>(&sred[rowg][c4]) = wsac;
        if ((t & 7) == 0) dred[rowg][h] = dsum;
        __syncthreads();
        if (t < 128) {
            float s = 0.f;
            #pragma unroll
            for (int g = 0; g < 8; ++g) s += sred[g][t];
            atomicAdd(&J.o1[t], s);
        }
        if (t < 4) {
            float s = 0.f;
            #pragma unroll
            for (int g = 0; g < 8; ++g) s += dred[g][t];
            atomicAdd(&J.o2[t], s);
        }
    }
}

// ---------------- state linear: out[128] = feat[K] @ W[K][128] + b ----------------
__global__ void state_lin(const float* __restrict__ feat, const float* __restrict__ W,
                          const float* __restrict__ b, float* __restrict__ out, int K)
{
    int n = threadIdx.x;   // 128 threads
    float acc = b[n];
    for (int k = 0; k < K; ++k) acc += feat[k] * W[k * 128 + n];
    out[n] = acc;
}

// ---- tiny: per-head dots of Wh_in with the two state dst-attn vectors ----
__global__ void edot2(const float* __restrict__ Wh_inb, const float* __restrict__ aP,
                      const float* __restrict__ aA, float* __restrict__ edsP,
                      float* __restrict__ edsA)
{
    int t = threadIdx.x;   // 128
    int l = t & 31;
    float v = Wh_inb[t];
    float p = v * aP[t];
    float q = v * aA[t];
    #pragma unroll
    for (int off = 16; off; off >>= 1) {
        p += __shfl_xor(p, off, 32);
        q += __shfl_xor(q, off, 32);
    }
    if (l == 0) { edsP[t >> 5] = p; edsA[t >> 5] = q; }
}

// ---------------- CSR build: 4-way batched histogram / scatter ----------------
struct EdgeJobs { const int* src[4]; const int* dst[4]; int* srcsOut[4]; };

__launch_bounds__(256)
__global__ void hist4(EdgeJobs ej, int* __restrict__ counts)
{
    int y = blockIdx.y;
    int e = blockIdx.x * 256 + threadIdx.x;
    if (e < EDG) atomicAdd(&counts[y * NODE_STRIDE + ej.dst[y][e]], 1);
}

__launch_bounds__(1024)
__global__ void scan4(const int* __restrict__ counts, int* __restrict__ offsets,
                      int* __restrict__ cursor, int n)
{
    const int* cnt = counts + blockIdx.x * NODE_STRIDE;
    int* off = offsets + blockIdx.x * NODE_STRIDE;
    int* cur = cursor + blockIdx.x * NODE_STRIDE;
    int t = threadIdx.x;
    int lane = t & 63, wv = t >> 6;
    __shared__ int wsum[16];
    __shared__ int carry_s;
    if (t == 0) { carry_s = 0; off[0] = 0; }
    __syncthreads();
    for (int base = 0; base < n; base += 1024) {
        int i = base + t;
        int v = (i < n) ? cnt[i] : 0;
        int x = v;
        #pragma unroll
        for (int o = 1; o < 64; o <<= 1) {
            int y = __shfl_up(x, o, 64);
            if (lane >= o) x += y;
        }
        if (lane == 63) wsum[wv] = x;
        __syncthreads();
        if (wv == 0) {
            int y = (lane < 16) ? wsum[lane] : 0;
            #pragma unroll
            for (int o = 1; o < 16; o <<= 1) {
                int z = __shfl_up(y, o, 64);
                if (lane >= o) y += z;
            }
            if (lane < 16) wsum[lane] = y;
        }
        __syncthreads();
        int add = carry_s + (wv > 0 ? wsum[wv - 1] : 0);
        int incl = x + add;
        if (i < n) { off[i + 1] = incl; cur[i] = incl - v; }
        __syncthreads();
        if (t == 0) carry_s += wsum[15];
        __syncthreads();
    }
}

__launch_bounds__(256)
__global__ void scatter4(EdgeJobs ej, int* __restrict__ cursor)
{
    int y = blockIdx.y;
    int e = blockIdx.x * 256 + threadIdx.x;
    if (e >= EDG) return;
    int d = ej.dst[y][e];
    int pos = atomicAdd(&cursor[y * NODE_STRIDE + d], 1);
    ej.srcsOut[y][pos] = ej.src[y][e];
}

// ---- aggregate both edge types (bf16 tables); normalize, add self, relu ----
__launch_bounds__(256)
__global__ void aggregate2(const unsigned* __restrict__ Wh0, const int* __restrict__ off0,
                           const int* __restrict__ srcs0, const float* __restrict__ es0,
                           const float* __restrict__ ed0,
                           const unsigned* __restrict__ Wh1, const int* __restrict__ off1,
                           const int* __restrict__ srcs1, const float* __restrict__ es1,
                           const float* __restrict__ ed1,
                           float* __restrict__ out, int n)
{
    int lane = threadIdx.x & 63;
    int node = (blockIdx.x * blockDim.x + threadIdx.x) >> 6;
    if (node >= n) return;
    const int h = lane >> 4;
    float accX0 = 0.f, accY0 = 0.f, d0 = 0.f;
    float accX1 = 0.f, accY1 = 0.f, d1 = 0.f;
    {
        float edv = ed0[node * 4 + h];
        int b = off0[node], e = off0[node + 1];
        int i = b;
        for (; i + 4 <= e; i += 4) {
            int s0 = srcs0[i], s1 = srcs0[i+1], s2 = srcs0[i+2], s3 = srcs0[i+3];
            float w0 = __expf(lrelu(es0[s0*4 + h] + edv));
            float w1 = __expf(lrelu(es0[s1*4 + h] + edv));
            float w2 = __expf(lrelu(es0[s2*4 + h] + edv));
            float w3 = __expf(lrelu(es0[s3*4 + h] + edv));
            unsigned x0 = Wh0[(size_t)s0*64 + lane];
            unsigned x1 = Wh0[(size_t)s1*64 + lane];
            unsigned x2 = Wh0[(size_t)s2*64 + lane];
            unsigned x3 = Wh0[(size_t)s3*64 + lane];
            accX0 += w0*__uint_as_float(x0<<16) + w1*__uint_as_float(x1<<16)
                   + w2*__uint_as_float(x2<<16) + w3*__uint_as_float(x3<<16);
            accY0 += w0*__uint_as_float(x0&0xffff0000u) + w1*__uint_as_float(x1&0xffff0000u)
                   + w2*__uint_as_float(x2&0xffff0000u) + w3*__uint_as_float(x3&0xffff0000u);
            d0 += w0 + w1 + w2 + w3;
        }
        for (; i < e; ++i) {
            int s = srcs0[i];
            float w = __expf(lrelu(es0[s*4 + h] + edv));
            unsigned x = Wh0[(size_t)s*64 + lane];
            accX0 += w * __uint_as_float(x<<16);
            accY0 += w * __uint_as_float(x&0xffff0000u);
            d0 += w;
        }
    }
    {
        float edv = ed1[node * 4 + h];
        int b = off1[node], e = off1[node + 1];
        int i = b;
        for (; i + 4 <= e; i += 4) {
            int s0 = srcs1[i], s1 = srcs1[i+1], s2 = srcs1[i+2], s3 = srcs1[i+3];
            float w0 = __expf(lrelu(es1[s0*4 + h] + edv));
            float w1 = __expf(lrelu(es1[s1*4 + h] + edv));
            float w2 = __expf(lrelu(es1[s2*4 + h] + edv));
            float w3 = __expf(lrelu(es1[s3*4 + h] + edv));
            unsigned x0 = Wh1[(size_t)s0*64 + lane];
            unsigned x1 = Wh1[(size_t)s1*64 + lane];
            unsigned x2 = Wh1[(size_t)s2*64 + lane];
            unsigned x3 = Wh1[(size_t)s3*64 + lane];
            accX1 += w0*__uint_as_float(x0<<16) + w1*__uint_as_float(x1<<16)
                   + w2*__uint_as_float(x2<<16) + w3*__uint_as_float(x3<<16);
            accY1 += w0*__uint_as_float(x0&0xffff0000u) + w1*__uint_as_float(x1&0xffff0000u)
                   + w2*__uint_as_float(x2&0xffff0000u) + w3*__uint_as_float(x3&0xffff0000u);
            d1 += w0 + w1 + w2 + w3;
        }
        for (; i < e; ++i) {
            int s = srcs1[i];
            float w = __expf(lrelu(es1[s*4 + h] + edv));
            unsigned x = Wh1[(size_t)s*64 + lane];
            accX1 += w * __uint_as_float(x<<16);
            accY1 += w * __uint_as_float(x&0xffff0000u);
            d1 += w;
        }
    }
    float i0 = d0 > 0.f ? 1.f / d0 : 0.f;
    float i1 = d1 > 0.f ? 1.f / d1 : 0.f;
    float2* op = reinterpret_cast<float2*>(out + (size_t)node * 128) + lane;
    float2 o = *op;
    o.x += accX0 * i0 + accX1 * i1;
    o.y += accY0 * i0 + accY1 * i1;
    o.x = o.x > 0.f ? o.x : 0.f;
    o.y = o.y > 0.f ? o.y : 0.f;
    *op = o;
}

__global__ void finalize_state(const float* __restrict__ Wh_in, const float* __restrict__ SS0,
                               const float* __restrict__ dS0, const float* __restrict__ SS1,
                               const float* __restrict__ dS1, float* __restrict__ out)
{
    int t = threadIdx.x;   // 128
    int h = t >> 5;
    float v0 = dS0[h]; float i0 = v0 > 0.f ? 1.f / v0 : 0.f;
    float v1 = dS1[h]; float i1 = v1 > 0.f ? 1.f / v1 : 0.f;
    float v = Wh_in[t] + SS0[t] * i0 + SS1[t] * i1;
    out[t] = v > 0.f ? v : 0.f;
}

extern "C" void kernel_launch(void* const* d_in, const int* in_sizes, int n_in,
                              void* d_out, int out_size, void* d_ws, size_t ws_size,
                              hipStream_t stream)
{
    const float* feat_P = (const float*)d_in[0];
    const float* feat_A = (const float*)d_in[1];
    const float* feat_state = (const float*)d_in[2];
    const float* W_P   = (const float*)d_in[3];  const float* b_P   = (const float*)d_in[4];
    const float* W_A   = (const float*)d_in[5];  const float* b_A   = (const float*)d_in[6];
    const float* W_p2p = (const float*)d_in[7];  const float* b_p2p = (const float*)d_in[8];
    const float* W_p2a = (const float*)d_in[9];  const float* b_p2a = (const float*)d_in[10];
    const float* W_a2p = (const float*)d_in[11]; const float* b_a2p = (const float*)d_in[12];
    const float* W_a2a = (const float*)d_in[13]; const float* b_a2a = (const float*)d_in[14];
    const float* W_p2s = (const float*)d_in[15]; const float* b_p2s = (const float*)d_in[16];
    const float* W_a2s = (const float*)d_in[17]; const float* b_a2s = (const float*)d_in[18];
    const float* W_in  = (const float*)d_in[19]; const float* b_in  = (const float*)d_in[20];
    const float* at_p2p_s = (const float*)d_in[21]; const float* at_p2p_d = (const float*)d_in[22];
    const float* at_p2a_s = (const float*)d_in[23]; const float* at_p2a_d = (const float*)d_in[24];
    const float* at_a2p_s = (const float*)d_in[25]; const float* at_a2p_d = (const float*)d_in[26];
    const float* at_a2a_s = (const float*)d_in[27]; const float* at_a2a_d = (const float*)d_in[28];
    const float* at_p2s_s = (const float*)d_in[29]; const float* at_p2s_d = (const float*)d_in[30];
    const float* at_a2s_s = (const float*)d_in[31]; const float* at_a2s_d = (const float*)d_in[32];
    const int* src_p2p = (const int*)d_in[33]; const int* dst_p2p = (const int*)d_in[34];
    const int* src_p2a = (const int*)d_in[35]; const int* dst_p2a = (const int*)d_in[36];
    const int* src_a2p = (const int*)d_in[37]; const int* dst_a2p = (const int*)d_in[38];
    const int* src_a2a = (const int*)d_in[39]; const int* dst_a2a = (const int*)d_in[40];
    float* out = (float*)d_out;

    // ---------------- workspace layout ----------------
    char* base = (char*)d_ws;
    unsigned short* bT_p2p = (unsigned short*)base; base += (size_t)NP * HD * 2;  // 7.68 MB each
    unsigned short* bT_a2p = (unsigned short*)base; base += (size_t)NA * HD * 2;
    unsigned short* bT_p2a = (unsigned short*)base; base += (size_t)NP * HD * 2;
    unsigned short* bT_a2a = (unsigned short*)base; base += (size_t)NA * HD * 2;
    int* srcs_p2p = (int*)base;    base += (size_t)EDG * 4;
    int* srcs_a2p = (int*)base;    base += (size_t)EDG * 4;
    int* srcs_p2a = (int*)base;    base += (size_t)EDG * 4;
    int* srcs_a2a = (int*)base;    base += (size_t)EDG * 4;
    float* es_p2p = (float*)base;  base += NP * 4 * 4;
    float* es_a2p = (float*)base;  base += NA * 4 * 4;
    float* es_p2a = (float*)base;  base += NP * 4 * 4;
    float* es_a2a = (float*)base;  base += NA * 4 * 4;
    float* ed_p2p = (float*)base;  base += NP * 4 * 4;
    float* ed_a2p = (float*)base;  base += NP * 4 * 4;
    float* ed_p2a = (float*)base;  base += NA * 4 * 4;
    float* ed_a2a = (float*)base;  base += NA * 4 * 4;
    int*   counts = (int*)base;    base += 4 * NODE_STRIDE * 4;
    int*   cursor = (int*)base;    base += 4 * NODE_STRIDE * 4;
    int*   offs   = (int*)base;    base += 4 * NODE_STRIDE * 4;
    float* Wh_inb = (float*)base;  base += 128 * 4;
    float* SS0    = (float*)base;  base += 128 * 4;               // SS0,SS1,dS0,dS1 contiguous
    float* SS1    = (float*)base;  base += 128 * 4;
    float* dS0    = (float*)base;  base += 4 * 4;
    float* dS1    = (float*)base;  base += 4 * 4;
    float* edsP   = (float*)base;  base += 4 * 4;
    float* edsA   = (float*)base;  base += 4 * 4;
    size_t needed = (size_t)(base - (char*)d_ws);   // ~42 MB
    if (ws_size < needed) return;   // diagnostic guard

    int* off_p2p = offs;
    int* off_a2p = offs + NODE_STRIDE;
    int* off_p2a = offs + 2 * NODE_STRIDE;
    int* off_a2a = offs + 3 * NODE_STRIDE;

    float* outP = out;
    float* outA = out + (size_t)NP * HD;
    float* outS = out + (size_t)(NP + NA) * HD;

    const dim3 B(256);
    const int gNodeW64 = (NP * 64 + 255) / 256;   // 7500
    const int gEdgeT = (EDG + 255) / 256;         // 1563

    // ---- CSR build ----
    EdgeJobs ej;
    ej.src[0] = src_p2p; ej.dst[0] = dst_p2p; ej.srcsOut[0] = srcs_p2p;
    ej.src[1] = src_a2p; ej.dst[1] = dst_a2p; ej.srcsOut[1] = srcs_a2p;
    ej.src[2] = src_p2a; ej.dst[2] = dst_p2a; ej.srcsOut[2] = srcs_p2a;
    ej.src[3] = src_a2a; ej.dst[3] = dst_a2a; ej.srcsOut[3] = srcs_a2a;
    hipMemsetAsync(counts, 0, 4 * NODE_STRIDE * sizeof(int), stream);
    hist4<<<dim3(gEdgeT, 4), B, 0, stream>>>(ej, counts);
    scan4<<<4, 1024, 0, stream>>>(counts, offs, cursor, NP);
    scatter4<<<dim3(gEdgeT, 4), B, 0, stream>>>(ej, cursor);

    // ---- state prologue ----
    hipMemsetAsync(SS0, 0, (128 + 128 + 4 + 4) * sizeof(float), stream);
    state_lin<<<1, 128, 0, stream>>>(feat_state, W_in, b_in, Wh_inb, 64);
    edot2<<<1, 128, 0, stream>>>(Wh_inb, at_p2s_d, at_a2s_d, edsP, edsA);

    // ---- MFMA bf16: all 4 edge-type tables in one dispatch ----
    {
        MJobs m;
        m.j[0] = { feat_P, W_p2p, b_p2p, bT_p2p, at_p2p_s, es_p2p };
        m.j[1] = { feat_A, W_a2p, b_a2p, bT_a2p, at_a2p_s, es_a2p };
        m.j[2] = { feat_P, W_p2a, b_p2a, bT_p2a, at_p2a_s, es_p2a };
        m.j[3] = { feat_A, W_a2a, b_a2a, bT_a2a, at_a2a_s, es_a2a };
        gemm_mfma<<<dim3(MBPJ, 4), B, 0, stream>>>(m);
    }
    // ---- fp32: selves (mode 0) + state (mode 2) ----
    {
        GJobs g;
        g.j[0] = { feat_P, W_P,   b_P,   outP,    at_p2p_d, ed_p2p, at_a2p_d, ed_a2p, 0 };
        g.j[1] = { feat_A, W_A,   b_A,   outA,    at_p2a_d, ed_p2a, at_a2a_d, ed_a2a, 0 };
        g.j[2] = { feat_P, W_p2s, b_p2s, nullptr, at_p2s_s, SS0,    edsP,     dS0,    2 };
        g.j[3] = { feat_A, W_a2s, b_a2s, nullptr, at_a2s_s, SS1,    edsA,     dS1,    2 };
        gemm_multi<<<dim3(BPJ, 4), B, 0, stream>>>(g);
    }

    // ---- aggregates (bf16 gathers) ----
    aggregate2<<<gNodeW64, B, 0, stream>>>((const unsigned*)bT_p2p, off_p2p, srcs_p2p, es_p2p, ed_p2p,
                                           (const unsigned*)bT_a2p, off_a2p, srcs_a2p, es_a2p, ed_a2p,
                                           outP, NP);
    aggregate2<<<gNodeW64, B, 0, stream>>>((const unsigned*)bT_p2a, off_p2a, srcs_p2a, es_p2a, ed_p2a,
                                           (const unsigned*)bT_a2a, off_a2a, srcs_a2a, es_a2a, ed_a2a,
                                           outA, NA);

    finalize_state<<<1, 128, 0, stream>>>(Wh_inb, SS0, dS0, SS1, dS1, outS);
}